// Round 4
// baseline (1556.633 us; speedup 1.0000x reference)
//
#include <hip/hip_runtime.h>

#define CIN  512
#define HDIM 16
#define CODIM 40

__device__ __forceinline__ void fma4(float4& a, float s, float4 b) {
  a.x = fmaf(s, b.x, a.x);
  a.y = fmaf(s, b.y, a.y);
  a.z = fmaf(s, b.z, a.z);
  a.w = fmaf(s, b.w, a.w);
}

__device__ __forceinline__ float4 red4(float4 v) {
  v.x += __shfl_xor(v.x, 1); v.y += __shfl_xor(v.y, 1);
  v.z += __shfl_xor(v.z, 1); v.w += __shfl_xor(v.w, 1);
  v.x += __shfl_xor(v.x, 2); v.y += __shfl_xor(v.y, 2);
  v.z += __shfl_xor(v.z, 2); v.w += __shfl_xor(v.w, 2);
  return v;
}

__device__ __forceinline__ void atomAdd(float* p, float v) {
  __hip_atomic_fetch_add(p, v, __ATOMIC_RELAXED, __HIP_MEMORY_SCOPE_AGENT);
}

// deg[i] = 1 (self-loop weight)
__global__ void k_init_deg(float* __restrict__ deg, int N) {
  int i = blockIdx.x * 256 + threadIdx.x;
  if (i < N) deg[i] = 1.0f;
}

// deg[dst[e]] += w[e]
__global__ void k_deg_scatter(const int* __restrict__ dst, const float* __restrict__ w,
                              float* __restrict__ deg, int E) {
  int e = blockIdx.x * 256 + threadIdx.x;
  if (e < E) atomAdd(&deg[dst[e]], w[e]);
}

// dis = rsqrt(deg); deg >= 1 always (self loop), so no zero-guard needed
__global__ void k_rsqrt(float* __restrict__ deg, int N) {
  int i = blockIdx.x * 256 + threadIdx.x;
  if (i < N) deg[i] = rsqrtf(deg[i]);
}

// y1[n][:] = dis[n] * (x[n][:] @ W1);  acc1 = copy of y1 (self-loop init)
// 4 threads per node, each handles a strided quarter of K, shfl-reduce.
__global__ __launch_bounds__(256) void k_gemm1(
    const float* __restrict__ x, const float* __restrict__ W1,
    const float* __restrict__ dis, float* __restrict__ y1,
    float* __restrict__ acc1, int N) {
  __shared__ float w1s[CIN * HDIM];  // 32 KB
  int t = threadIdx.x;
  #pragma unroll
  for (int i = 0; i < (CIN * HDIM) / 256; ++i) w1s[t + i * 256] = W1[t + i * 256];
  __syncthreads();

  int node = blockIdx.x * 64 + (t >> 2);
  int q = t & 3;
  if (node >= N) return;

  const float4* x4 = (const float4*)x + (size_t)node * (CIN / 4);
  float4 a0 = make_float4(0.f, 0.f, 0.f, 0.f), a1 = a0, a2 = a0, a3 = a0;

  #pragma unroll 4
  for (int kk = 0; kk < 32; ++kk) {
    // lane q reads float4 #(kk*4+q) of its node's row -> wave reads contiguous 64B lines
    float4 xv = x4[kk * 4 + q];
    // this float4 covers k = (kk*4+q)*4 .. +3 -> W1 rows kb..kb+3
    const float4* wr = (const float4*)w1s + (size_t)(kk * 16 + q * 4) * 4;
    fma4(a0, xv.x, wr[0]);  fma4(a1, xv.x, wr[1]);  fma4(a2, xv.x, wr[2]);  fma4(a3, xv.x, wr[3]);
    fma4(a0, xv.y, wr[4]);  fma4(a1, xv.y, wr[5]);  fma4(a2, xv.y, wr[6]);  fma4(a3, xv.y, wr[7]);
    fma4(a0, xv.z, wr[8]);  fma4(a1, xv.z, wr[9]);  fma4(a2, xv.z, wr[10]); fma4(a3, xv.z, wr[11]);
    fma4(a0, xv.w, wr[12]); fma4(a1, xv.w, wr[13]); fma4(a2, xv.w, wr[14]); fma4(a3, xv.w, wr[15]);
  }
  a0 = red4(a0); a1 = red4(a1); a2 = red4(a2); a3 = red4(a3);

  float dsc = dis[node];
  float4 sel = (q == 0) ? a0 : (q == 1) ? a1 : (q == 2) ? a2 : a3;
  sel.x *= dsc; sel.y *= dsc; sel.z *= dsc; sel.w *= dsc;
  ((float4*)y1)[(size_t)node * 4 + q]   = sel;
  ((float4*)acc1)[(size_t)node * 4 + q] = sel;
}

// acc[dst[e]][:] += w[e] * vals[src[e]][:]   (16-wide, 4 threads per edge)
__global__ void k_scatter16(const int* __restrict__ src, const int* __restrict__ dst,
                            const float* __restrict__ w, const float* __restrict__ vals,
                            float* __restrict__ acc, int E) {
  int tid = blockIdx.x * 256 + threadIdx.x;
  int e = tid >> 2, q = tid & 3;
  if (e >= E) return;
  int s = src[e], d = dst[e];
  float we = w[e];
  float4 v = ((const float4*)vals)[(size_t)s * 4 + q];
  float* a = acc + (size_t)d * HDIM + q * 4;
  atomAdd(a + 0, we * v.x);
  atomAdd(a + 1, we * v.y);
  atomAdd(a + 2, we * v.z);
  atomAdd(a + 3, we * v.w);
}

// z = dis * relu(dis*acc1 + b1); write z in-place over acc1, and acc2 = z (self-loop init)
__global__ void k_z(const float* __restrict__ dis, const float* __restrict__ b1,
                    float* __restrict__ acc1, float* __restrict__ acc2, int N16) {
  int i = blockIdx.x * 256 + threadIdx.x;
  if (i >= N16) return;
  int n = i >> 4;
  float a = dis[n];
  float v = fmaf(a, acc1[i], b1[i & 15]);
  v = fmaxf(v, 0.f);
  float zv = a * v;
  acc1[i] = zv;
  acc2[i] = zv;
}

// out[n][:] = log_softmax( (dis[n]*acc2[n][:]) @ W2 + b2 )
__global__ __launch_bounds__(256) void k_final(
    const float* __restrict__ acc2, const float* __restrict__ dis,
    const float* __restrict__ W2, const float* __restrict__ b2,
    float* __restrict__ out, int N) {
  __shared__ float w2s[HDIM * CODIM + CODIM];
  int t = threadIdx.x;
  for (int i = t; i < HDIM * CODIM; i += 256) w2s[i] = W2[i];
  if (t < CODIM) w2s[HDIM * CODIM + t] = b2[t];
  __syncthreads();

  int n = blockIdx.x * 256 + t;
  if (n >= N) return;

  const float4* a4 = (const float4*)acc2 + (size_t)n * 4;
  float d = dis[n];
  float g[HDIM];
  *(float4*)(g + 0)  = a4[0];
  *(float4*)(g + 4)  = a4[1];
  *(float4*)(g + 8)  = a4[2];
  *(float4*)(g + 12) = a4[3];
  #pragma unroll
  for (int h = 0; h < HDIM; ++h) g[h] *= d;

  float v[CODIM];
  #pragma unroll
  for (int j = 0; j < CODIM; ++j) v[j] = w2s[HDIM * CODIM + j];
  #pragma unroll
  for (int h = 0; h < HDIM; ++h) {
    float gh = g[h];
    #pragma unroll
    for (int j = 0; j < CODIM; ++j) v[j] = fmaf(gh, w2s[h * CODIM + j], v[j]);
  }

  float m = v[0];
  #pragma unroll
  for (int j = 1; j < CODIM; ++j) m = fmaxf(m, v[j]);
  float sum = 0.f;
  #pragma unroll
  for (int j = 0; j < CODIM; ++j) sum += __expf(v[j] - m);
  float lse = __logf(sum) + m;
  float* o = out + (size_t)n * CODIM;
  #pragma unroll
  for (int j = 0; j < CODIM; ++j) o[j] = v[j] - lse;
}

extern "C" void kernel_launch(void* const* d_in, const int* in_sizes, int n_in,
                              void* d_out, int out_size, void* d_ws, size_t ws_size,
                              hipStream_t stream) {
  const float* x  = (const float*)d_in[0];
  const int*   ei = (const int*)d_in[1];   // [2, E] row-major: row0=src, row1=dst
  const float* ew = (const float*)d_in[2];
  const float* W1 = (const float*)d_in[3];
  const float* b1 = (const float*)d_in[4];
  const float* W2 = (const float*)d_in[5];
  const float* b2 = (const float*)d_in[6];
  float* out = (float*)d_out;

  int N = in_sizes[0] / CIN;
  int E = in_sizes[2];
  const int* src = ei;
  const int* dst = ei + E;

  float* ws_f = (float*)d_ws;
  size_t NA = ((size_t)N + 63) & ~(size_t)63;
  float* dis  = ws_f;             // N
  float* y1   = dis  + NA;        // N*16
  float* acc1 = y1   + NA * 16;   // N*16  (becomes z in-place)
  float* acc2 = acc1 + NA * 16;   // N*16

  int gN   = (N + 255) / 256;
  int gE   = (E + 255) / 256;
  int gN16 = (N * 16 + 255) / 256;
  int gE4  = (E * 4 + 255) / 256;
  int gG   = (N + 63) / 64;

  k_init_deg<<<gN, 256, 0, stream>>>(dis, N);
  k_deg_scatter<<<gE, 256, 0, stream>>>(dst, ew, dis, E);
  k_rsqrt<<<gN, 256, 0, stream>>>(dis, N);
  k_gemm1<<<gG, 256, 0, stream>>>(x, W1, dis, y1, acc1, N);
  k_scatter16<<<gE4, 256, 0, stream>>>(src, dst, ew, y1, acc1, E);
  k_z<<<gN16, 256, 0, stream>>>(dis, b1, acc1, acc2, N * 16);
  k_scatter16<<<gE4, 256, 0, stream>>>(src, dst, ew, acc1, acc2, E);
  k_final<<<gN, 256, 0, stream>>>(acc2, dis, W2, b2, out, N);
}

// Round 5
// 580.519 us; speedup vs baseline: 2.6814x; 2.6814x over previous
//
#include <hip/hip_runtime.h>

#define CIN  512
#define HDIM 16
#define CODIM 40

__device__ __forceinline__ void fma4(float4& a, float s, float4 b) {
  a.x = fmaf(s, b.x, a.x);
  a.y = fmaf(s, b.y, a.y);
  a.z = fmaf(s, b.z, a.z);
  a.w = fmaf(s, b.w, a.w);
}

__device__ __forceinline__ float4 red4(float4 v) {
  v.x += __shfl_xor(v.x, 1); v.y += __shfl_xor(v.y, 1);
  v.z += __shfl_xor(v.z, 1); v.w += __shfl_xor(v.w, 1);
  v.x += __shfl_xor(v.x, 2); v.y += __shfl_xor(v.y, 2);
  v.z += __shfl_xor(v.z, 2); v.w += __shfl_xor(v.w, 2);
  return v;
}

// ---------- CSR build ----------
__global__ void k_zero(int* __restrict__ p, int n) {
  int i = blockIdx.x * 256 + threadIdx.x;
  if (i < n) p[i] = 0;
}

__global__ void k_count(const int* __restrict__ dst, int* __restrict__ cnt, int E) {
  int e = blockIdx.x * 256 + threadIdx.x;
  if (e < E) atomicAdd(&cnt[dst[e]], 1);
}

// block sums over 1024-element chunks
__global__ __launch_bounds__(256) void k_scanA(const int* __restrict__ cnt,
                                               int* __restrict__ bsum, int N) {
  __shared__ int red[256];
  int t = threadIdx.x;
  int base = blockIdx.x * 1024 + t * 4;
  int s = 0;
  #pragma unroll
  for (int j = 0; j < 4; ++j) { int i = base + j; if (i < N) s += cnt[i]; }
  red[t] = s;
  __syncthreads();
  #pragma unroll
  for (int off = 128; off > 0; off >>= 1) {
    if (t < off) red[t] += red[t + off];
    __syncthreads();
  }
  if (t == 0) bsum[blockIdx.x] = red[0];
}

// serial exclusive scan of block sums (B <= 128); also writes rowptr[N] = total
__global__ void k_scanB(int* __restrict__ bsum, int* __restrict__ rowptr, int B, int N) {
  int acc = 0;
  for (int i = 0; i < B; ++i) { int v = bsum[i]; bsum[i] = acc; acc += v; }
  rowptr[N] = acc;
}

// per-chunk exclusive scan + block offset -> rowptr, cursor
__global__ __launch_bounds__(256) void k_scanC(const int* __restrict__ cnt,
                                               const int* __restrict__ bsumx,
                                               int* __restrict__ rowptr,
                                               int* __restrict__ cursor, int N) {
  __shared__ int ts[256];
  int t = threadIdx.x;
  int base = blockIdx.x * 1024 + t * 4;
  int c[4]; int s = 0;
  #pragma unroll
  for (int j = 0; j < 4; ++j) { int i = base + j; c[j] = (i < N) ? cnt[i] : 0; s += c[j]; }
  ts[t] = s;
  __syncthreads();
  #pragma unroll
  for (int off = 1; off < 256; off <<= 1) {
    int v = (t >= off) ? ts[t - off] : 0;
    __syncthreads();
    ts[t] += v;
    __syncthreads();
  }
  int ex = ts[t] - s + bsumx[blockIdx.x];
  #pragma unroll
  for (int j = 0; j < 4; ++j) {
    int i = base + j;
    if (i < N) { rowptr[i] = ex; cursor[i] = ex; }
    ex += c[j];
  }
}

__global__ void k_fill(const int* __restrict__ src, const int* __restrict__ dst,
                       const float* __restrict__ w, int* __restrict__ cursor,
                       int2* __restrict__ csr, int E) {
  int e = blockIdx.x * 256 + threadIdx.x;
  if (e >= E) return;
  int d = dst[e];
  int pos = atomicAdd(&cursor[d], 1);
  csr[pos] = make_int2(src[e], __float_as_int(w[e]));
}

// dis[n] = rsqrt(1 + sum_{row n} w)
__global__ void k_dis(const int* __restrict__ rowptr, const int2* __restrict__ csr,
                      float* __restrict__ dis, int N) {
  int n = blockIdx.x * 256 + threadIdx.x;
  if (n >= N) return;
  int beg = rowptr[n], end = rowptr[n + 1];
  float s = 1.0f;
  for (int i = beg; i < end; ++i) s += __int_as_float(csr[i].y);
  dis[n] = rsqrtf(s);
}

// ---------- layer compute ----------
// y1[n][:] = dis[n] * (x[n][:] @ W1)
__global__ __launch_bounds__(256) void k_gemm1(
    const float* __restrict__ x, const float* __restrict__ W1,
    const float* __restrict__ dis, float* __restrict__ y1, int N) {
  __shared__ float w1s[CIN * HDIM];  // 32 KB
  int t = threadIdx.x;
  #pragma unroll
  for (int i = 0; i < (CIN * HDIM) / 256; ++i) w1s[t + i * 256] = W1[t + i * 256];
  __syncthreads();

  int node = blockIdx.x * 64 + (t >> 2);
  int q = t & 3;
  if (node >= N) return;

  const float4* x4 = (const float4*)x + (size_t)node * (CIN / 4);
  float4 a0 = make_float4(0.f, 0.f, 0.f, 0.f), a1 = a0, a2 = a0, a3 = a0;

  #pragma unroll 4
  for (int kk = 0; kk < 32; ++kk) {
    float4 xv = x4[kk * 4 + q];
    const float4* wr = (const float4*)w1s + (size_t)(kk * 16 + q * 4) * 4;
    fma4(a0, xv.x, wr[0]);  fma4(a1, xv.x, wr[1]);  fma4(a2, xv.x, wr[2]);  fma4(a3, xv.x, wr[3]);
    fma4(a0, xv.y, wr[4]);  fma4(a1, xv.y, wr[5]);  fma4(a2, xv.y, wr[6]);  fma4(a3, xv.y, wr[7]);
    fma4(a0, xv.z, wr[8]);  fma4(a1, xv.z, wr[9]);  fma4(a2, xv.z, wr[10]); fma4(a3, xv.z, wr[11]);
    fma4(a0, xv.w, wr[12]); fma4(a1, xv.w, wr[13]); fma4(a2, xv.w, wr[14]); fma4(a3, xv.w, wr[15]);
  }
  a0 = red4(a0); a1 = red4(a1); a2 = red4(a2); a3 = red4(a3);

  float dsc = dis[node];
  float4 sel = (q == 0) ? a0 : (q == 1) ? a1 : (q == 2) ? a2 : a3;
  sel.x *= dsc; sel.y *= dsc; sel.z *= dsc; sel.w *= dsc;
  ((float4*)y1)[(size_t)node * 4 + q] = sel;
}

// acc[d][:] = vals[d][:] + sum_{e in row d} w_e * vals[src_e][:]   (4 lanes/node)
__global__ __launch_bounds__(256) void k_aggregate(
    const int* __restrict__ rowptr, const int2* __restrict__ csr,
    const float* __restrict__ vals, float* __restrict__ acc, int N) {
  int t = threadIdx.x;
  int node = blockIdx.x * 64 + (t >> 2);
  int q = t & 3;
  if (node >= N) return;
  int beg = rowptr[node], end = rowptr[node + 1];
  const float4* v4 = (const float4*)vals;
  float4 a = v4[(size_t)node * 4 + q];  // self-loop (weight 1 in pre-scaled space)
  for (int i = beg; i < end; ++i) {
    int2 e = csr[i];
    float w = __int_as_float(e.y);
    float4 v = v4[(size_t)e.x * 4 + q];
    fma4(a, w, v);
  }
  ((float4*)acc)[(size_t)node * 4 + q] = a;
}

// z = dis * relu(dis*acc + b1), in place
__global__ void k_z(const float* __restrict__ dis, const float* __restrict__ b1,
                    float* __restrict__ acc1, int N16) {
  int i = blockIdx.x * 256 + threadIdx.x;
  if (i >= N16) return;
  int n = i >> 4;
  float a = dis[n];
  float v = fmaf(a, acc1[i], b1[i & 15]);
  v = fmaxf(v, 0.f);
  acc1[i] = a * v;
}

// out[n][:] = log_softmax( (dis[n]*acc2[n][:]) @ W2 + b2 )
__global__ __launch_bounds__(256) void k_final(
    const float* __restrict__ acc2, const float* __restrict__ dis,
    const float* __restrict__ W2, const float* __restrict__ b2,
    float* __restrict__ out, int N) {
  __shared__ float w2s[HDIM * CODIM + CODIM];
  int t = threadIdx.x;
  for (int i = t; i < HDIM * CODIM; i += 256) w2s[i] = W2[i];
  if (t < CODIM) w2s[HDIM * CODIM + t] = b2[t];
  __syncthreads();

  int n = blockIdx.x * 256 + t;
  if (n >= N) return;

  const float4* a4 = (const float4*)acc2 + (size_t)n * 4;
  float d = dis[n];
  float g[HDIM];
  *(float4*)(g + 0)  = a4[0];
  *(float4*)(g + 4)  = a4[1];
  *(float4*)(g + 8)  = a4[2];
  *(float4*)(g + 12) = a4[3];
  #pragma unroll
  for (int h = 0; h < HDIM; ++h) g[h] *= d;

  float v[CODIM];
  #pragma unroll
  for (int j = 0; j < CODIM; ++j) v[j] = w2s[HDIM * CODIM + j];
  #pragma unroll
  for (int h = 0; h < HDIM; ++h) {
    float gh = g[h];
    #pragma unroll
    for (int j = 0; j < CODIM; ++j) v[j] = fmaf(gh, w2s[h * CODIM + j], v[j]);
  }

  float m = v[0];
  #pragma unroll
  for (int j = 1; j < CODIM; ++j) m = fmaxf(m, v[j]);
  float sum = 0.f;
  #pragma unroll
  for (int j = 0; j < CODIM; ++j) sum += __expf(v[j] - m);
  float lse = __logf(sum) + m;
  float* o = out + (size_t)n * CODIM;
  #pragma unroll
  for (int j = 0; j < CODIM; ++j) o[j] = v[j] - lse;
}

extern "C" void kernel_launch(void* const* d_in, const int* in_sizes, int n_in,
                              void* d_out, int out_size, void* d_ws, size_t ws_size,
                              hipStream_t stream) {
  const float* x  = (const float*)d_in[0];
  const int*   ei = (const int*)d_in[1];   // [2, E]: row0=src, row1=dst
  const float* ew = (const float*)d_in[2];
  const float* W1 = (const float*)d_in[3];
  const float* b1 = (const float*)d_in[4];
  const float* W2 = (const float*)d_in[5];
  const float* b2 = (const float*)d_in[6];
  float* out = (float*)d_out;

  int N = in_sizes[0] / CIN;
  int E = in_sizes[2];
  const int* src = ei;
  const int* dst = ei + E;

  // ---- workspace layout ----
  size_t NA = ((size_t)N + 255) & ~(size_t)255;  // padded to 256 elems
  int*  rowptr = (int*)d_ws;          // NA (+1 fits in pad)
  int*  cursor = rowptr + NA + 256;   // NA
  int*  cnt    = cursor + NA;         // NA
  int*  bsum   = cnt + NA;            // 256
  int2* csr    = (int2*)(bsum + 256); // E entries (8B each), 8B-aligned
  float* dis   = (float*)(csr + E);   // NA
  float* y1    = dis + NA;            // NA*16
  float* acc1  = y1  + NA * 16;       // NA*16  (becomes z in place)
  float* acc2  = acc1 + NA * 16;      // NA*16

  int gN   = (N + 255) / 256;
  int gE   = (E + 255) / 256;
  int gN16 = (N * 16 + 255) / 256;
  int gG   = (N + 63) / 64;
  int B    = (N + 1023) / 1024;       // scan chunks

  // CSR build
  k_zero <<<gN, 256, 0, stream>>>(cnt, N);
  k_count<<<gE, 256, 0, stream>>>(dst, cnt, E);
  k_scanA<<<B, 256, 0, stream>>>(cnt, bsum, N);
  k_scanB<<<1, 1, 0, stream>>>(bsum, rowptr, B, N);
  k_scanC<<<B, 256, 0, stream>>>(cnt, bsum, rowptr, cursor, N);
  k_fill <<<gE, 256, 0, stream>>>(src, dst, ew, cursor, csr, E);
  k_dis  <<<gN, 256, 0, stream>>>(rowptr, csr, dis, N);

  // two GCN layers
  k_gemm1    <<<gG, 256, 0, stream>>>(x, W1, dis, y1, N);
  k_aggregate<<<gG, 256, 0, stream>>>(rowptr, csr, y1, acc1, N);
  k_z        <<<gN16, 256, 0, stream>>>(dis, b1, acc1, N * 16);
  k_aggregate<<<gG, 256, 0, stream>>>(rowptr, csr, acc1, acc2, N);
  k_final    <<<gN, 256, 0, stream>>>(acc2, dis, W2, b2, out, N);
}